// Round 3
// baseline (155.158 us; speedup 1.0000x reference)
//
#include <hip/hip_runtime.h>
#include <hip/hip_bf16.h>

// out = spline(x) @ proj_w^T + x @ res_w^T + proj_b
// A_bf16 = [spline(x) | x] : (16384, 2048),  Bcat_bf16 = [proj_w | res_w] : (1024, 2048)

#define IN_F   1024
#define OUT_F  1024
#define KNOTS  12
#define M_ROWS 16384
#define GK     2048

// ---- GEMM params: 256x256 tile, BK=32, 8 waves, 4-deep LDS pipeline ----
#define BM   256
#define BN   256
#define BKT  32
#define NT   (GK / BKT)     // 64 K-tiles
#define NBUF 4

typedef __attribute__((ext_vector_type(8))) __bf16 bf16x8;
typedef __attribute__((ext_vector_type(4))) float  f32x4;

__device__ __forceinline__ unsigned short f2bf(float v) {
    unsigned int u = __float_as_uint(v);
    u = (u + 0x7fffu + ((u >> 16) & 1u)) >> 16;   // RNE
    return (unsigned short)u;
}

__device__ __forceinline__ void gload16(const void* g, void* l) {
    __builtin_amdgcn_global_load_lds(
        (const __attribute__((address_space(1))) void*)g,
        (__attribute__((address_space(3))) void*)l, 16, 0, 0);
}

// ---------------- prep: sort knots, fold sigmoid, build float4 Hermite table
// H[f][k] = { mc[k], mc[k+1], mt[k]*dx_k, mt[k+1]*dx_k },  k = 0..10
__global__ __launch_bounds__(256) void prep_kernel(
    const float* __restrict__ grid, const float* __restrict__ coeffs,
    const float* __restrict__ tangents, const float* __restrict__ alive,
    float* __restrict__ gmin, float* __restrict__ scale, float4* __restrict__ H)
{
    int f = blockIdx.x * blockDim.x + threadIdx.x;
    if (f >= IN_F) return;
    float g[KNOTS], c[KNOTS], t[KNOTS], a[KNOTS];
    for (int i = 0; i < KNOTS; ++i) {
        g[i] = grid[f*KNOTS+i];  c[i] = coeffs[f*KNOTS+i];
        t[i] = tangents[f*KNOTS+i]; a[i] = alive[f*KNOTS+i];
    }
    for (int i = 1; i < KNOTS; ++i) {       // stable insertion sort on g
        float gk=g[i], ck=c[i], tk=t[i], ak=a[i];
        int j = i-1;
        while (j >= 0 && g[j] > gk) { g[j+1]=g[j]; c[j+1]=c[j]; t[j+1]=t[j]; a[j+1]=a[j]; --j; }
        g[j+1]=gk; c[j+1]=ck; t[j+1]=tk; a[j+1]=ak;
    }
    float mcl[KNOTS], mtl[KNOTS];
    for (int i = 0; i < KNOTS; ++i) {
        float s = 1.f / (1.f + expf(-a[i]));
        mcl[i] = c[i]*s;  mtl[i] = t[i]*s;
    }
    gmin[f] = g[0];
    float grange = fmaxf(g[KNOTS-1] - g[0], 1e-6f);
    scale[f] = (float)(KNOTS-1) / grange;
    for (int k = 0; k < KNOTS-1; ++k) {
        float dx = fmaxf(g[k+1]-g[k], 1e-6f);
        H[(size_t)f*KNOTS + k] = make_float4(mcl[k], mcl[k+1], mtl[k]*dx, mtl[k+1]*dx);
    }
    H[(size_t)f*KNOTS + KNOTS-1] = make_float4(0.f, 0.f, 0.f, 0.f);
}

// ---------------- spline + cast:  A = [spline(x) | x]  bf16 -----------------
// 256 threads; thread owns 4 consecutive features (covers all 1024); 32 rows/blk.
// H table is 192 KB -> L2-resident; gather 16B per eval straight from global.
#define SPB 32
__global__ __launch_bounds__(256) void spline_kernel(const float* __restrict__ x,
    const float* __restrict__ gmin, const float* __restrict__ scale,
    const float4* __restrict__ H, unsigned short* __restrict__ A)
{
    const int tid = threadIdx.x;
    const int f0  = tid * 4;
    const float4 gm4 = *reinterpret_cast<const float4*>(gmin + f0);
    const float4 sc4 = *reinterpret_cast<const float4*>(scale + f0);
    const float gms[4] = {gm4.x, gm4.y, gm4.z, gm4.w};
    const float scs[4] = {sc4.x, sc4.y, sc4.z, sc4.w};
    const int r0 = blockIdx.x * SPB;
    for (int r = 0; r < SPB; ++r) {
        const int row = r0 + r;
        const float4 xv = *reinterpret_cast<const float4*>(x + (size_t)row*IN_F + f0);
        const float xs[4] = {xv.x, xv.y, xv.z, xv.w};
        ushort4 so, xo;
        unsigned short* sp = (unsigned short*)&so;
        unsigned short* xp = (unsigned short*)&xo;
        #pragma unroll
        for (int j = 0; j < 4; ++j) {
            const float xi = xs[j];
            float xn = (xi - gms[j]) * scs[j];
            xn = fminf(fmaxf(xn, 0.f), (float)(KNOTS-1));
            int idx = (int)xn;  idx = idx > (KNOTS-2) ? (KNOTS-2) : idx;
            const float tt = xn - (float)idx;
            const float4 h = H[(size_t)(f0+j)*KNOTS + idx];
            const float t2 = tt*tt, t3 = t2*tt;
            const float h00 =  2.f*t3 - 3.f*t2 + 1.f;
            const float h01 = -2.f*t3 + 3.f*t2;
            const float h10 =  t3 - 2.f*t2 + tt;
            const float h11 =  t3 - t2;
            sp[j] = f2bf(h00*h.x + h01*h.y + h10*h.z + h11*h.w);
            xp[j] = f2bf(xi);
        }
        const size_t base = (size_t)row * GK;
        *reinterpret_cast<ushort4*>(A + base + f0)        = so;
        *reinterpret_cast<ushort4*>(A + base + IN_F + f0) = xo;
    }
}

// ---------------- B cast: Bcat = [proj_w | res_w] bf16 ----------------------
__global__ __launch_bounds__(256) void bcast_kernel(
    const float* __restrict__ P, const float* __restrict__ R,
    unsigned short* __restrict__ Bc)
{
    int g = blockIdx.x*256 + threadIdx.x;          // OUT_F*GK/4 total
    int n  = g >> 9;
    int k4 = (g & 511) * 4;
    const float* src = (k4 < IN_F) ? (P + (size_t)n*IN_F + k4)
                                   : (R + (size_t)n*IN_F + (k4 - IN_F));
    float4 v = *reinterpret_cast<const float4*>(src);
    ushort4 o;
    o.x = f2bf(v.x); o.y = f2bf(v.y); o.z = f2bf(v.z); o.w = f2bf(v.w);
    *reinterpret_cast<ushort4*>(Bc + (size_t)n*GK + k4) = o;
}

// ---------------- GEMM: C = A @ Bcat^T + bias ------------------------------
// 256x256 tile, BK=32, 512 threads (8 waves: 2M x 4N, each 128x64 out).
// 4-deep circular LDS buffer; stage tile t+3 during tile t; counted vmcnt(8)
// (never 0 mid-loop); 2 barriers per K-tile; ds_read issue + stage + MFMA in
// the SAME region so the compiler interleaves lgkmcnt waits with MFMAs.
// XOR swizzle (c ^= (row>>1)&3) on global source AND ds_read (involution).
__global__ __launch_bounds__(512, 2) void gemm_kernel(
    const unsigned short* __restrict__ A, const unsigned short* __restrict__ B,
    const float* __restrict__ bias, float* __restrict__ C)
{
    __shared__ unsigned short sA[NBUF][BM*BKT];   // 4 x 16 KiB
    __shared__ unsigned short sB[NBUF][BN*BKT];   // 4 x 16 KiB  => 128 KiB total

    const int tid  = threadIdx.x;
    // XCD-bijective swizzle: 256 wgs, 8 XCDs, 32 per chunk
    const int wg   = blockIdx.x;
    const int swz  = (wg & 7) * 32 + (wg >> 3);
    const int by   = swz >> 2;         // 0..63  M-tile
    const int bx   = swz & 3;          // 0..3   N-tile

    const int lane = tid & 63;
    const int wave = tid >> 6;         // 0..7
    const int wr   = wave >> 2;        // 0..1  M-wave (128 rows)
    const int wc   = wave & 3;         // 0..3  N-wave (64 cols)
    const int lr   = lane & 15;
    const int bsel = lane >> 4;        // 16B block within 64B row

    const size_t aBase = (size_t)by * BM * GK;
    const size_t bBase = (size_t)bx * BN * GK;

    f32x4 acc[8][4] = {};

    auto stageA = [&](int t, int buf) {
        const int k0 = t * BKT;
        #pragma unroll
        for (int i = 0; i < 2; ++i) {
            const int L = i*512 + tid;
            const int row = L >> 2, c = L & 3;
            const int cs = c ^ ((row >> 1) & 3);
            gload16(A + aBase + (size_t)row*GK + k0 + cs*8, &sA[buf][(size_t)L*8]);
        }
    };
    auto stageB = [&](int t, int buf) {
        const int k0 = t * BKT;
        #pragma unroll
        for (int i = 0; i < 2; ++i) {
            const int L = i*512 + tid;
            const int row = L >> 2, c = L & 3;
            const int cs = c ^ ((row >> 1) & 3);
            gload16(B + bBase + (size_t)row*GK + k0 + cs*8, &sB[buf][(size_t)L*8]);
        }
    };
    auto ldA = [&](int buf, int row) -> bf16x8 {
        const int cs = bsel ^ ((row >> 1) & 3);
        return *reinterpret_cast<const bf16x8*>(&sA[buf][row*BKT + cs*8]);
    };
    auto ldB = [&](int buf, int row) -> bf16x8 {
        const int cs = bsel ^ ((row >> 1) & 3);
        return *reinterpret_cast<const bf16x8*>(&sB[buf][row*BKT + cs*8]);
    };

    // prologue: stage tiles 0,1,2  (12 loads in flight)
    stageA(0,0); stageB(0,0);
    stageA(1,1); stageB(1,1);
    stageA(2,2); stageB(2,2);

    for (int t = 0; t < NT; ++t) {
        const int buf = t & 3;
        // outstanding here: tiles t, t+1, t+2 (12 loads). Drain only tile t.
        if (t < NT-2)        asm volatile("s_waitcnt vmcnt(8)" ::: "memory");
        else if (t == NT-2)  asm volatile("s_waitcnt vmcnt(4)" ::: "memory");
        else                 asm volatile("s_waitcnt vmcnt(0)" ::: "memory");
        __builtin_amdgcn_s_barrier();

        // ---- half 1: ds_reads + stageA(t+3) + 16 MFMA, one region ----
        bf16x8 a0[4], bfr[4];
        #pragma unroll
        for (int m = 0; m < 4; ++m) a0[m] = ldA(buf, wr*128 + m*16 + lr);
        #pragma unroll
        for (int n = 0; n < 4; ++n) bfr[n] = ldB(buf, wc*64 + n*16 + lr);
        if (t + 3 < NT) stageA(t+3, (t+3) & 3);

        __builtin_amdgcn_s_setprio(1);
        #pragma unroll
        for (int m = 0; m < 4; ++m)
            #pragma unroll
            for (int n = 0; n < 4; ++n)
                acc[m][n] = __builtin_amdgcn_mfma_f32_16x16x32_bf16(a0[m], bfr[n], acc[m][n], 0, 0, 0);
        __builtin_amdgcn_s_setprio(0);
        __builtin_amdgcn_s_barrier();     // alignment only

        // ---- half 2: ds_reads + stageB(t+3) + 16 MFMA ----
        bf16x8 a1[4];
        #pragma unroll
        for (int m = 0; m < 4; ++m) a1[m] = ldA(buf, wr*128 + 64 + m*16 + lr);
        if (t + 3 < NT) stageB(t+3, (t+3) & 3);

        __builtin_amdgcn_s_setprio(1);
        #pragma unroll
        for (int m = 0; m < 4; ++m)
            #pragma unroll
            for (int n = 0; n < 4; ++n)
                acc[4+m][n] = __builtin_amdgcn_mfma_f32_16x16x32_bf16(a1[m], bfr[n], acc[4+m][n], 0, 0, 0);
        __builtin_amdgcn_s_setprio(0);
    }

    // epilogue: C = acc + bias   (C/D map: col = lane&15, row = (lane>>4)*4 + r)
    const int r0 = (lane >> 4) * 4;
    #pragma unroll
    for (int n = 0; n < 4; ++n) {
        const int col = bx*BN + wc*64 + n*16 + lr;
        const float bv = bias[col];
        #pragma unroll
        for (int m = 0; m < 8; ++m) {
            const int grow = by*BM + wr*128 + m*16 + r0;
            #pragma unroll
            for (int r = 0; r < 4; ++r)
                C[(size_t)(grow + r)*OUT_F + col] = acc[m][n][r] + bv;
        }
    }
}

// ---------------- fallback (ws too small): fused fp32, slow but correct -----
__global__ __launch_bounds__(256) void fallback_kernel(
    const float* __restrict__ x, const float* __restrict__ P,
    const float* __restrict__ R, const float* __restrict__ pb,
    const float* __restrict__ gmin, const float* __restrict__ scale,
    const float4* __restrict__ H, float* __restrict__ out)
{
    __shared__ float s_s[IN_F];
    __shared__ float s_x[IN_F];
    int row = blockIdx.x;
    const float* xr = x + (size_t)row*IN_F;
    for (int f = threadIdx.x; f < IN_F; f += 256) {
        float xi = xr[f];
        float xn = (xi - gmin[f]) * scale[f];
        xn = fminf(fmaxf(xn, 0.f), (float)(KNOTS-1));
        int idx = (int)xn;  idx = idx > (KNOTS-2) ? (KNOTS-2) : idx;
        float tt = xn - (float)idx;
        float4 h = H[(size_t)f*KNOTS + idx];
        float t2 = tt*tt, t3 = t2*tt;
        s_s[f] = (2.f*t3-3.f*t2+1.f)*h.x + (-2.f*t3+3.f*t2)*h.y
               + (t3-2.f*t2+tt)*h.z + (t3-t2)*h.w;
        s_x[f] = xi;
    }
    __syncthreads();
    for (int j = 0; j < 4; ++j) {
        int o = threadIdx.x + j*256;
        const float* Pr = P + (size_t)o*IN_F;
        const float* Rr = R + (size_t)o*IN_F;
        float acc = pb[o];
        for (int f = 0; f < IN_F; ++f)
            acc = fmaf(s_s[f], Pr[f], fmaf(s_x[f], Rr[f], acc));
        out[(size_t)row*OUT_F + o] = acc;
    }
}

extern "C" void kernel_launch(void* const* d_in, const int* in_sizes, int n_in,
                              void* d_out, int out_size, void* d_ws, size_t ws_size,
                              hipStream_t stream) {
    const float* x         = (const float*)d_in[0];
    const float* grid      = (const float*)d_in[1];
    const float* coeffs    = (const float*)d_in[2];
    const float* tangents  = (const float*)d_in[3];
    const float* knotalive = (const float*)d_in[4];
    const float* proj_w    = (const float*)d_in[5];
    const float* proj_b    = (const float*)d_in[6];
    const float* res_w     = (const float*)d_in[7];
    float* out = (float*)d_out;

    const size_t needB  = (size_t)OUT_F * GK * 2;                 // 4 MiB
    const size_t needA  = (size_t)M_ROWS * GK * 2;                // 64 MiB
    const size_t needT  = ((size_t)IN_F*2 + (size_t)IN_F*KNOTS*4) * 4;  // gmin+scale+H

    char* ws = (char*)d_ws;
    if (ws_size >= needB + needA + needT) {
        unsigned short* Bcat = (unsigned short*)ws;
        unsigned short* Abuf = (unsigned short*)(ws + needB);
        float*  gmin = (float*)(ws + needB + needA);
        float*  scl  = gmin + IN_F;
        float4* H    = (float4*)(scl + IN_F);

        prep_kernel<<<(IN_F+255)/256, 256, 0, stream>>>(grid, coeffs, tangents, knotalive,
                                                        gmin, scl, H);
        bcast_kernel<<<(OUT_F*GK/4)/256, 256, 0, stream>>>(proj_w, res_w, Bcat);
        spline_kernel<<<M_ROWS/SPB, 256, 0, stream>>>(x, gmin, scl, H, Abuf);
        gemm_kernel<<<(M_ROWS/BM)*(OUT_F/BN), 512, 0, stream>>>(Abuf, Bcat, proj_b, out);
    } else {
        float*  gmin = (float*)ws;
        float*  scl  = gmin + IN_F;
        float4* H    = (float4*)(scl + IN_F);
        prep_kernel<<<(IN_F+255)/256, 256, 0, stream>>>(grid, coeffs, tangents, knotalive,
                                                        gmin, scl, H);
        fallback_kernel<<<M_ROWS, 256, 0, stream>>>(x, proj_w, res_w, proj_b,
                                                    gmin, scl, H, out);
    }
}

// Round 4
// 109.784 us; speedup vs baseline: 1.4133x; 1.4133x over previous
//
#include <hip/hip_runtime.h>
#include <hip/hip_bf16.h>

// out = spline(x) @ proj_w^T + x @ res_w^T + proj_b
// A_bf16 = [spline(x) | x] : (16384, 2048),  Bcat_bf16 = [proj_w | res_w] : (1024, 2048)

#define IN_F   1024
#define OUT_F  1024
#define KNOTS  12
#define M_ROWS 16384
#define GK     2048

// ---- GEMM params: 256x256 tile, BK=32, 8 waves, 4-deep LDS pipeline ----
#define BM   256
#define BN   256
#define BKT  32
#define NT   (GK / BKT)     // 64 K-tiles
#define NBUF 4

typedef __attribute__((ext_vector_type(8))) __bf16 bf16x8;
typedef __attribute__((ext_vector_type(4))) float  f32x4;

__device__ __forceinline__ unsigned short f2bf(float v) {
    unsigned int u = __float_as_uint(v);
    u = (u + 0x7fffu + ((u >> 16) & 1u)) >> 16;   // RNE
    return (unsigned short)u;
}

__device__ __forceinline__ void gload16(const void* g, void* l) {
    __builtin_amdgcn_global_load_lds(
        (const __attribute__((address_space(1))) void*)g,
        (__attribute__((address_space(3))) void*)l, 16, 0, 0);
}

// ---------------- prep: sort knots, fold sigmoid, build float4 Hermite table
// H[f][k] = { mc[k], mc[k+1], mt[k]*dx_k, mt[k+1]*dx_k },  k = 0..10
__global__ __launch_bounds__(256) void prep_kernel(
    const float* __restrict__ grid, const float* __restrict__ coeffs,
    const float* __restrict__ tangents, const float* __restrict__ alive,
    float* __restrict__ gmin, float* __restrict__ scale, float4* __restrict__ H)
{
    int f = blockIdx.x * blockDim.x + threadIdx.x;
    if (f >= IN_F) return;
    float g[KNOTS], c[KNOTS], t[KNOTS], a[KNOTS];
    for (int i = 0; i < KNOTS; ++i) {
        g[i] = grid[f*KNOTS+i];  c[i] = coeffs[f*KNOTS+i];
        t[i] = tangents[f*KNOTS+i]; a[i] = alive[f*KNOTS+i];
    }
    for (int i = 1; i < KNOTS; ++i) {       // stable insertion sort on g
        float gk=g[i], ck=c[i], tk=t[i], ak=a[i];
        int j = i-1;
        while (j >= 0 && g[j] > gk) { g[j+1]=g[j]; c[j+1]=c[j]; t[j+1]=t[j]; a[j+1]=a[j]; --j; }
        g[j+1]=gk; c[j+1]=ck; t[j+1]=tk; a[j+1]=ak;
    }
    float mcl[KNOTS], mtl[KNOTS];
    for (int i = 0; i < KNOTS; ++i) {
        float s = 1.f / (1.f + expf(-a[i]));
        mcl[i] = c[i]*s;  mtl[i] = t[i]*s;
    }
    gmin[f] = g[0];
    float grange = fmaxf(g[KNOTS-1] - g[0], 1e-6f);
    scale[f] = (float)(KNOTS-1) / grange;
    for (int k = 0; k < KNOTS-1; ++k) {
        float dx = fmaxf(g[k+1]-g[k], 1e-6f);
        H[(size_t)f*KNOTS + k] = make_float4(mcl[k], mcl[k+1], mtl[k]*dx, mtl[k+1]*dx);
    }
    H[(size_t)f*KNOTS + KNOTS-1] = make_float4(0.f, 0.f, 0.f, 0.f);
}

// ---------------- spline + cast:  A = [spline(x) | x]  bf16 -----------------
// grid (M_ROWS/64, IN_F/256), 256 threads. Tables for the block's 256-feature
// slice staged in LDS (52 KiB, stride 13 pad). Lane owns 4 consecutive
// features: float4 x-load (16B/lane), ushort4 A-stores (8B/lane). Waves
// stride over 64 rows -> 16 independent iterations each (ILP + TLP).
#define SROWS 64
#define HPAD  13
__global__ __launch_bounds__(256) void spline_kernel(const float* __restrict__ x,
    const float* __restrict__ gmin, const float* __restrict__ scale,
    const float4* __restrict__ H, unsigned short* __restrict__ A)
{
    __shared__ float4 sH[256 * HPAD];     // 52 KiB
    __shared__ float  sGm[256], sSc[256];
    const int tid  = threadIdx.x;
    const int fblk = blockIdx.y * 256;
    #pragma unroll
    for (int k = 0; k < KNOTS; ++k) sH[tid*HPAD + k] = H[(size_t)(fblk+tid)*KNOTS + k];
    sGm[tid] = gmin[fblk+tid];
    sSc[tid] = scale[fblk+tid];
    __syncthreads();

    const int wave = tid >> 6, lane = tid & 63;
    const int f0 = lane * 4;              // feature offset within slice
    const float4 gm4 = *reinterpret_cast<const float4*>(&sGm[f0]);
    const float4 sc4 = *reinterpret_cast<const float4*>(&sSc[f0]);
    const float gms[4] = {gm4.x, gm4.y, gm4.z, gm4.w};
    const float scs[4] = {sc4.x, sc4.y, sc4.z, sc4.w};
    const int r0 = blockIdx.x * SROWS;

    #pragma unroll 2
    for (int r = wave; r < SROWS; r += 4) {
        const int row = r0 + r;
        const float4 xv = *reinterpret_cast<const float4*>(x + (size_t)row*IN_F + fblk + f0);
        const float xs[4] = {xv.x, xv.y, xv.z, xv.w};
        ushort4 so, xo;
        unsigned short* sp = (unsigned short*)&so;
        unsigned short* xp = (unsigned short*)&xo;
        #pragma unroll
        for (int j = 0; j < 4; ++j) {
            const float xi = xs[j];
            float xn = (xi - gms[j]) * scs[j];
            xn = fminf(fmaxf(xn, 0.f), (float)(KNOTS-1));
            int idx = (int)xn;  idx = idx > (KNOTS-2) ? (KNOTS-2) : idx;
            const float tt = xn - (float)idx;
            const float4 h = sH[(f0+j)*HPAD + idx];
            const float t2 = tt*tt, t3 = t2*tt;
            const float h00 =  2.f*t3 - 3.f*t2 + 1.f;
            const float h01 = -2.f*t3 + 3.f*t2;
            const float h10 =  t3 - 2.f*t2 + tt;
            const float h11 =  t3 - t2;
            sp[j] = f2bf(h00*h.x + h01*h.y + h10*h.z + h11*h.w);
            xp[j] = f2bf(xi);
        }
        const size_t base = (size_t)row * GK + fblk + f0;
        *reinterpret_cast<ushort4*>(A + base)        = so;
        *reinterpret_cast<ushort4*>(A + base + IN_F) = xo;
    }
}

// ---------------- B cast: Bcat = [proj_w | res_w] bf16 ----------------------
__global__ __launch_bounds__(256) void bcast_kernel(
    const float* __restrict__ P, const float* __restrict__ R,
    unsigned short* __restrict__ Bc)
{
    int g = blockIdx.x*256 + threadIdx.x;          // OUT_F*GK/4 total
    int n  = g >> 9;
    int k4 = (g & 511) * 4;
    const float* src = (k4 < IN_F) ? (P + (size_t)n*IN_F + k4)
                                   : (R + (size_t)n*IN_F + (k4 - IN_F));
    float4 v = *reinterpret_cast<const float4*>(src);
    ushort4 o;
    o.x = f2bf(v.x); o.y = f2bf(v.y); o.z = f2bf(v.z); o.w = f2bf(v.w);
    *reinterpret_cast<ushort4*>(Bc + (size_t)n*GK + k4) = o;
}

// ---------------- GEMM: C = A @ Bcat^T + bias ------------------------------
// 256x256 tile, BK=32, 512 threads (8 waves: 2M x 4N, each 128x64 out).
// 4-deep circular LDS buffer; stage tile t+3 during tile t; counted vmcnt(8)
// (never 0 mid-loop); 2 barriers per K-tile; ds_read issue + stage + MFMA in
// the SAME region so the compiler interleaves lgkmcnt waits with MFMAs.
// XOR swizzle (c ^= (row>>1)&3) on global source AND ds_read (involution).
__global__ __launch_bounds__(512, 2) void gemm_kernel(
    const unsigned short* __restrict__ A, const unsigned short* __restrict__ B,
    const float* __restrict__ bias, float* __restrict__ C)
{
    __shared__ unsigned short sA[NBUF][BM*BKT];   // 4 x 16 KiB
    __shared__ unsigned short sB[NBUF][BN*BKT];   // 4 x 16 KiB  => 128 KiB total

    const int tid  = threadIdx.x;
    // XCD-bijective swizzle: 256 wgs, 8 XCDs, 32 per chunk
    const int wg   = blockIdx.x;
    const int swz  = (wg & 7) * 32 + (wg >> 3);
    const int by   = swz >> 2;         // 0..63  M-tile
    const int bx   = swz & 3;          // 0..3   N-tile

    const int lane = tid & 63;
    const int wave = tid >> 6;         // 0..7
    const int wr   = wave >> 2;        // 0..1  M-wave (128 rows)
    const int wc   = wave & 3;         // 0..3  N-wave (64 cols)
    const int lr   = lane & 15;
    const int bsel = lane >> 4;        // 16B block within 64B row

    const size_t aBase = (size_t)by * BM * GK;
    const size_t bBase = (size_t)bx * BN * GK;

    f32x4 acc[8][4] = {};

    auto stageA = [&](int t, int buf) {
        const int k0 = t * BKT;
        #pragma unroll
        for (int i = 0; i < 2; ++i) {
            const int L = i*512 + tid;
            const int row = L >> 2, c = L & 3;
            const int cs = c ^ ((row >> 1) & 3);
            gload16(A + aBase + (size_t)row*GK + k0 + cs*8, &sA[buf][(size_t)L*8]);
        }
    };
    auto stageB = [&](int t, int buf) {
        const int k0 = t * BKT;
        #pragma unroll
        for (int i = 0; i < 2; ++i) {
            const int L = i*512 + tid;
            const int row = L >> 2, c = L & 3;
            const int cs = c ^ ((row >> 1) & 3);
            gload16(B + bBase + (size_t)row*GK + k0 + cs*8, &sB[buf][(size_t)L*8]);
        }
    };
    auto ldA = [&](int buf, int row) -> bf16x8 {
        const int cs = bsel ^ ((row >> 1) & 3);
        return *reinterpret_cast<const bf16x8*>(&sA[buf][row*BKT + cs*8]);
    };
    auto ldB = [&](int buf, int row) -> bf16x8 {
        const int cs = bsel ^ ((row >> 1) & 3);
        return *reinterpret_cast<const bf16x8*>(&sB[buf][row*BKT + cs*8]);
    };

    // prologue: stage tiles 0,1,2  (12 loads in flight)
    stageA(0,0); stageB(0,0);
    stageA(1,1); stageB(1,1);
    stageA(2,2); stageB(2,2);

    for (int t = 0; t < NT; ++t) {
        const int buf = t & 3;
        // outstanding here: tiles t, t+1, t+2 (12 loads). Drain only tile t.
        if (t < NT-2)        asm volatile("s_waitcnt vmcnt(8)" ::: "memory");
        else if (t == NT-2)  asm volatile("s_waitcnt vmcnt(4)" ::: "memory");
        else                 asm volatile("s_waitcnt vmcnt(0)" ::: "memory");
        __builtin_amdgcn_s_barrier();

        // ---- half 1: ds_reads + stageA(t+3) + 16 MFMA, one region ----
        bf16x8 a0[4], bfr[4];
        #pragma unroll
        for (int m = 0; m < 4; ++m) a0[m] = ldA(buf, wr*128 + m*16 + lr);
        #pragma unroll
        for (int n = 0; n < 4; ++n) bfr[n] = ldB(buf, wc*64 + n*16 + lr);
        if (t + 3 < NT) stageA(t+3, (t+3) & 3);

        __builtin_amdgcn_s_setprio(1);
        #pragma unroll
        for (int m = 0; m < 4; ++m)
            #pragma unroll
            for (int n = 0; n < 4; ++n)
                acc[m][n] = __builtin_amdgcn_mfma_f32_16x16x32_bf16(a0[m], bfr[n], acc[m][n], 0, 0, 0);
        __builtin_amdgcn_s_setprio(0);
        __builtin_amdgcn_s_barrier();     // alignment only

        // ---- half 2: ds_reads + stageB(t+3) + 16 MFMA ----
        bf16x8 a1[4];
        #pragma unroll
        for (int m = 0; m < 4; ++m) a1[m] = ldA(buf, wr*128 + 64 + m*16 + lr);
        if (t + 3 < NT) stageB(t+3, (t+3) & 3);

        __builtin_amdgcn_s_setprio(1);
        #pragma unroll
        for (int m = 0; m < 4; ++m)
            #pragma unroll
            for (int n = 0; n < 4; ++n)
                acc[4+m][n] = __builtin_amdgcn_mfma_f32_16x16x32_bf16(a1[m], bfr[n], acc[4+m][n], 0, 0, 0);
        __builtin_amdgcn_s_setprio(0);
    }

    // epilogue: C = acc + bias   (C/D map: col = lane&15, row = (lane>>4)*4 + r)
    const int r0 = (lane >> 4) * 4;
    #pragma unroll
    for (int n = 0; n < 4; ++n) {
        const int col = bx*BN + wc*64 + n*16 + lr;
        const float bv = bias[col];
        #pragma unroll
        for (int m = 0; m < 8; ++m) {
            const int grow = by*BM + wr*128 + m*16 + r0;
            #pragma unroll
            for (int r = 0; r < 4; ++r)
                C[(size_t)(grow + r)*OUT_F + col] = acc[m][n][r] + bv;
        }
    }
}

// ---------------- fallback (ws too small): fused fp32, slow but correct -----
__global__ __launch_bounds__(256) void fallback_kernel(
    const float* __restrict__ x, const float* __restrict__ P,
    const float* __restrict__ R, const float* __restrict__ pb,
    const float* __restrict__ gmin, const float* __restrict__ scale,
    const float4* __restrict__ H, float* __restrict__ out)
{
    __shared__ float s_s[IN_F];
    __shared__ float s_x[IN_F];
    int row = blockIdx.x;
    const float* xr = x + (size_t)row*IN_F;
    for (int f = threadIdx.x; f < IN_F; f += 256) {
        float xi = xr[f];
        float xn = (xi - gmin[f]) * scale[f];
        xn = fminf(fmaxf(xn, 0.f), (float)(KNOTS-1));
        int idx = (int)xn;  idx = idx > (KNOTS-2) ? (KNOTS-2) : idx;
        float tt = xn - (float)idx;
        float4 h = H[(size_t)f*KNOTS + idx];
        float t2 = tt*tt, t3 = t2*tt;
        s_s[f] = (2.f*t3-3.f*t2+1.f)*h.x + (-2.f*t3+3.f*t2)*h.y
               + (t3-2.f*t2+tt)*h.z + (t3-t2)*h.w;
        s_x[f] = xi;
    }
    __syncthreads();
    for (int j = 0; j < 4; ++j) {
        int o = threadIdx.x + j*256;
        const float* Pr = P + (size_t)o*IN_F;
        const float* Rr = R + (size_t)o*IN_F;
        float acc = pb[o];
        for (int f = 0; f < IN_F; ++f)
            acc = fmaf(s_s[f], Pr[f], fmaf(s_x[f], Rr[f], acc));
        out[(size_t)row*OUT_F + o] = acc;
    }
}

extern "C" void kernel_launch(void* const* d_in, const int* in_sizes, int n_in,
                              void* d_out, int out_size, void* d_ws, size_t ws_size,
                              hipStream_t stream) {
    const float* x         = (const float*)d_in[0];
    const float* grid      = (const float*)d_in[1];
    const float* coeffs    = (const float*)d_in[2];
    const float* tangents  = (const float*)d_in[3];
    const float* knotalive = (const float*)d_in[4];
    const float* proj_w    = (const float*)d_in[5];
    const float* proj_b    = (const float*)d_in[6];
    const float* res_w     = (const float*)d_in[7];
    float* out = (float*)d_out;

    const size_t needB  = (size_t)OUT_F * GK * 2;                 // 4 MiB
    const size_t needA  = (size_t)M_ROWS * GK * 2;                // 64 MiB
    const size_t needT  = ((size_t)IN_F*2 + (size_t)IN_F*KNOTS*4) * 4;  // gmin+scale+H

    char* ws = (char*)d_ws;
    if (ws_size >= needB + needA + needT) {
        unsigned short* Bcat = (unsigned short*)ws;
        unsigned short* Abuf = (unsigned short*)(ws + needB);
        float*  gmin = (float*)(ws + needB + needA);
        float*  scl  = gmin + IN_F;
        float4* H    = (float4*)(scl + IN_F);

        prep_kernel<<<(IN_F+255)/256, 256, 0, stream>>>(grid, coeffs, tangents, knotalive,
                                                        gmin, scl, H);
        bcast_kernel<<<(OUT_F*GK/4)/256, 256, 0, stream>>>(proj_w, res_w, Bcat);
        spline_kernel<<<dim3(M_ROWS/SROWS, IN_F/256), 256, 0, stream>>>(x, gmin, scl, H, Abuf);
        gemm_kernel<<<(M_ROWS/BM)*(OUT_F/BN), 512, 0, stream>>>(Abuf, Bcat, proj_b, out);
    } else {
        float*  gmin = (float*)ws;
        float*  scl  = gmin + IN_F;
        float4* H    = (float4*)(scl + IN_F);
        prep_kernel<<<(IN_F+255)/256, 256, 0, stream>>>(grid, coeffs, tangents, knotalive,
                                                        gmin, scl, H);
        fallback_kernel<<<M_ROWS, 256, 0, stream>>>(x, proj_w, res_w, proj_b,
                                                    gmin, scl, H, out);
    }
}

// Round 5
// 107.490 us; speedup vs baseline: 1.4435x; 1.0213x over previous
//
#include <hip/hip_runtime.h>
#include <hip/hip_bf16.h>

// out = spline(x) @ proj_w^T + x @ res_w^T + proj_b
// A_bf16 = [spline(x) | x] : (16384, 2048),  Bcat_bf16 = [proj_w | res_w] : (1024, 2048)

#define IN_F   1024
#define OUT_F  1024
#define KNOTS  12
#define M_ROWS 16384
#define GK     2048

// ---- GEMM: 256x256 tile, BK=64, 8 waves, m201-style 4-phase/K-tile ----
#define BM   256
#define BN   256
#define BKT  64
#define NTK  (GK / BKT)     // 32 K-tiles

typedef __attribute__((ext_vector_type(8))) __bf16 bf16x8;
typedef __attribute__((ext_vector_type(4))) float  f32x4;

__device__ __forceinline__ unsigned short f2bf(float v) {
    unsigned int u = __float_as_uint(v);
    u = (u + 0x7fffu + ((u >> 16) & 1u)) >> 16;   // RNE
    return (unsigned short)u;
}

__device__ __forceinline__ void gload16(const void* g, void* l) {
    __builtin_amdgcn_global_load_lds(
        (const __attribute__((address_space(1))) void*)g,
        (__attribute__((address_space(3))) void*)l, 16, 0, 0);
}

// ---------------- prep: sort knots, fold sigmoid, build float4 Hermite table
__global__ __launch_bounds__(256) void prep_kernel(
    const float* __restrict__ grid, const float* __restrict__ coeffs,
    const float* __restrict__ tangents, const float* __restrict__ alive,
    float* __restrict__ gmin, float* __restrict__ scale, float4* __restrict__ H)
{
    int f = blockIdx.x * blockDim.x + threadIdx.x;
    if (f >= IN_F) return;
    float g[KNOTS], c[KNOTS], t[KNOTS], a[KNOTS];
    for (int i = 0; i < KNOTS; ++i) {
        g[i] = grid[f*KNOTS+i];  c[i] = coeffs[f*KNOTS+i];
        t[i] = tangents[f*KNOTS+i]; a[i] = alive[f*KNOTS+i];
    }
    for (int i = 1; i < KNOTS; ++i) {       // stable insertion sort on g
        float gk=g[i], ck=c[i], tk=t[i], ak=a[i];
        int j = i-1;
        while (j >= 0 && g[j] > gk) { g[j+1]=g[j]; c[j+1]=c[j]; t[j+1]=t[j]; a[j+1]=a[j]; --j; }
        g[j+1]=gk; c[j+1]=ck; t[j+1]=tk; a[j+1]=ak;
    }
    float mcl[KNOTS], mtl[KNOTS];
    for (int i = 0; i < KNOTS; ++i) {
        float s = 1.f / (1.f + expf(-a[i]));
        mcl[i] = c[i]*s;  mtl[i] = t[i]*s;
    }
    gmin[f] = g[0];
    float grange = fmaxf(g[KNOTS-1] - g[0], 1e-6f);
    scale[f] = (float)(KNOTS-1) / grange;
    for (int k = 0; k < KNOTS-1; ++k) {
        float dx = fmaxf(g[k+1]-g[k], 1e-6f);
        H[(size_t)f*KNOTS + k] = make_float4(mcl[k], mcl[k+1], mtl[k]*dx, mtl[k+1]*dx);
    }
    H[(size_t)f*KNOTS + KNOTS-1] = make_float4(0.f, 0.f, 0.f, 0.f);
}

// ---------------- spline + cast:  A = [spline(x) | x]  bf16 -----------------
#define SROWS 64
#define HPAD  13
__global__ __launch_bounds__(256) void spline_kernel(const float* __restrict__ x,
    const float* __restrict__ gmin, const float* __restrict__ scale,
    const float4* __restrict__ H, unsigned short* __restrict__ A)
{
    __shared__ float4 sH[256 * HPAD];     // 52 KiB
    __shared__ float  sGm[256], sSc[256];
    const int tid  = threadIdx.x;
    const int fblk = blockIdx.y * 256;
    #pragma unroll
    for (int k = 0; k < KNOTS; ++k) sH[tid*HPAD + k] = H[(size_t)(fblk+tid)*KNOTS + k];
    sGm[tid] = gmin[fblk+tid];
    sSc[tid] = scale[fblk+tid];
    __syncthreads();

    const int wave = tid >> 6, lane = tid & 63;
    const int f0 = lane * 4;
    const float4 gm4 = *reinterpret_cast<const float4*>(&sGm[f0]);
    const float4 sc4 = *reinterpret_cast<const float4*>(&sSc[f0]);
    const float gms[4] = {gm4.x, gm4.y, gm4.z, gm4.w};
    const float scs[4] = {sc4.x, sc4.y, sc4.z, sc4.w};
    const int r0 = blockIdx.x * SROWS;

    #pragma unroll 2
    for (int r = wave; r < SROWS; r += 4) {
        const int row = r0 + r;
        const float4 xv = *reinterpret_cast<const float4*>(x + (size_t)row*IN_F + fblk + f0);
        const float xs[4] = {xv.x, xv.y, xv.z, xv.w};
        ushort4 so, xo;
        unsigned short* sp = (unsigned short*)&so;
        unsigned short* xp = (unsigned short*)&xo;
        #pragma unroll
        for (int j = 0; j < 4; ++j) {
            const float xi = xs[j];
            float xn = (xi - gms[j]) * scs[j];
            xn = fminf(fmaxf(xn, 0.f), (float)(KNOTS-1));
            int idx = (int)xn;  idx = idx > (KNOTS-2) ? (KNOTS-2) : idx;
            const float tt = xn - (float)idx;
            const float4 h = sH[(f0+j)*HPAD + idx];
            const float t2 = tt*tt, t3 = t2*tt;
            const float h00 =  2.f*t3 - 3.f*t2 + 1.f;
            const float h01 = -2.f*t3 + 3.f*t2;
            const float h10 =  t3 - 2.f*t2 + tt;
            const float h11 =  t3 - t2;
            sp[j] = f2bf(h00*h.x + h01*h.y + h10*h.z + h11*h.w);
            xp[j] = f2bf(xi);
        }
        const size_t base = (size_t)row * GK + fblk + f0;
        *reinterpret_cast<ushort4*>(A + base)        = so;
        *reinterpret_cast<ushort4*>(A + base + IN_F) = xo;
    }
}

// ---------------- B cast: Bcat = [proj_w | res_w] bf16 ----------------------
__global__ __launch_bounds__(256) void bcast_kernel(
    const float* __restrict__ P, const float* __restrict__ R,
    unsigned short* __restrict__ Bc)
{
    int g = blockIdx.x*256 + threadIdx.x;
    int n  = g >> 9;
    int k4 = (g & 511) * 4;
    const float* src = (k4 < IN_F) ? (P + (size_t)n*IN_F + k4)
                                   : (R + (size_t)n*IN_F + (k4 - IN_F));
    float4 v = *reinterpret_cast<const float4*>(src);
    ushort4 o;
    o.x = f2bf(v.x); o.y = f2bf(v.y); o.z = f2bf(v.z); o.w = f2bf(v.w);
    *reinterpret_cast<ushort4*>(Bc + (size_t)n*GK + k4) = o;
}

// ---------------- GEMM: C = A @ Bcat^T + bias (8-phase m201 port) -----------
// Phases = output quadrants (mh, nh). Wave owns rows {mh*128 + wr*64 + m*16},
// cols {nh*128 + wc*32 + n*16} -> every wave reads A-half mh, B-half nh
// (wave-uniform). LDS halves restaged >=2 phases after their last reader.
// Per phase: ds_reads | stage 1 half-tile | counted vmcnt | barrier |
// lgkmcnt(0) | setprio(1) 16 MFMA setprio(0) | barrier.
__global__ __launch_bounds__(512, 2) void gemm_kernel(
    const unsigned short* __restrict__ A, const unsigned short* __restrict__ B,
    const float* __restrict__ bias, float* __restrict__ C)
{
    __shared__ unsigned short sA[2][2][128*64];   // [buf][half] 16KiB each
    __shared__ unsigned short sB[2][2][128*64];   // total 128 KiB

    const int tid  = threadIdx.x;
    const int wg   = blockIdx.x;                  // 256 wgs, %8==0 bijective
    const int swzb = (wg & 7) * 32 + (wg >> 3);
    const int by   = swzb >> 2;                   // 0..63
    const int bx   = swzb & 3;                    // 0..3

    const int lane = tid & 63;
    const int wave = tid >> 6;
    const int wr   = wave >> 2;      // 0..1
    const int wc   = wave & 3;       // 0..3
    const int lr   = lane & 15;
    const int lsl  = lane >> 4;      // 0..3

    const size_t aRow0 = (size_t)by * BM;
    const size_t bRow0 = (size_t)bx * BN;

    auto stage = [&](const unsigned short* __restrict__ G, size_t gRow0,
                     unsigned short* lds, int ts) {
        const int k0 = ts * BKT;
        #pragma unroll
        for (int i = 0; i < 2; ++i) {
            const int L16 = i*512 + tid;          // 16B units within half-tile
            const int lrow = L16 >> 3;            // 0..127
            const int ss = (L16 & 7) ^ (lrow & 7);  // pre-swizzled source slot
            gload16(G + (gRow0 + lrow)*GK + k0 + ss*8, lds + (size_t)L16*8);
        }
    };
    auto rd = [&](const unsigned short* s, int lrow, int ks) -> bf16x8 {
        const int sp = (ks*4 + lsl) ^ (lrow & 7);   // swizzled read slot
        return *reinterpret_cast<const bf16x8*>(s + lrow*64 + sp*8);
    };

    f32x4 acc[8][4] = {};
    bf16x8 a[4][2], bb[2][2][2];

    // prologue: A0(0) B0(0) A1(0) B1(0) A0(1) B0(1)  (12 gloads/wave)
    stage(A, aRow0,       &sA[0][0][0], 0);
    stage(B, bRow0,       &sB[0][0][0], 0);
    stage(A, aRow0 + 128, &sA[0][1][0], 0);
    stage(B, bRow0 + 128, &sB[0][1][0], 0);
    stage(A, aRow0,       &sA[1][0][0], 1);
    stage(B, bRow0,       &sB[1][0][0], 1);
    asm volatile("s_waitcnt vmcnt(8)" ::: "memory");   // A0(0),B0(0) landed
    __builtin_amdgcn_s_barrier();

    for (int t = 0; t < NTK; ++t) {
        const int b = t & 1;
        unsigned short* sA0 = &sA[b][0][0];
        unsigned short* sA1 = &sA[b][1][0];
        unsigned short* sB0 = &sB[b][0][0];
        unsigned short* sB1 = &sB[b][1][0];

        // ---- phase 0 (mh0, nh0): 12 ds_reads, stage A1(t+1) ----
        #pragma unroll
        for (int m = 0; m < 4; ++m)
            #pragma unroll
            for (int ks = 0; ks < 2; ++ks)
                a[m][ks] = rd(sA0, wr*64 + m*16 + lr, ks);
        #pragma unroll
        for (int n = 0; n < 2; ++n)
            #pragma unroll
            for (int ks = 0; ks < 2; ++ks)
                bb[0][n][ks] = rd(sB0, wc*32 + n*16 + lr, ks);
        if (t+1 < NTK) stage(A, aRow0 + 128, &sA[b^1][1][0], t+1);
        if (t == NTK-1) asm volatile("s_waitcnt vmcnt(0)" ::: "memory");
        else            asm volatile("s_waitcnt vmcnt(6)" ::: "memory");
        __builtin_amdgcn_s_barrier();
        asm volatile("s_waitcnt lgkmcnt(0)" ::: "memory");
        __builtin_amdgcn_sched_barrier(0);
        __builtin_amdgcn_s_setprio(1);
        #pragma unroll
        for (int m = 0; m < 4; ++m)
          #pragma unroll
          for (int n = 0; n < 2; ++n)
            #pragma unroll
            for (int ks = 0; ks < 2; ++ks)
                acc[m][n] = __builtin_amdgcn_mfma_f32_16x16x32_bf16(a[m][ks], bb[0][n][ks], acc[m][n], 0, 0, 0);
        __builtin_amdgcn_s_setprio(0);
        __builtin_amdgcn_s_barrier();

        // ---- phase 1 (mh0, nh1): 4 ds_reads, stage B1(t+1) ----
        #pragma unroll
        for (int n = 0; n < 2; ++n)
            #pragma unroll
            for (int ks = 0; ks < 2; ++ks)
                bb[1][n][ks] = rd(sB1, wc*32 + n*16 + lr, ks);
        if (t+1 < NTK) stage(B, bRow0 + 128, &sB[b^1][1][0], t+1);
        asm volatile("s_waitcnt vmcnt(10)" ::: "memory");
        __builtin_amdgcn_s_barrier();
        asm volatile("s_waitcnt lgkmcnt(0)" ::: "memory");
        __builtin_amdgcn_sched_barrier(0);
        __builtin_amdgcn_s_setprio(1);
        #pragma unroll
        for (int m = 0; m < 4; ++m)
          #pragma unroll
          for (int n = 0; n < 2; ++n)
            #pragma unroll
            for (int ks = 0; ks < 2; ++ks)
                acc[m][2+n] = __builtin_amdgcn_mfma_f32_16x16x32_bf16(a[m][ks], bb[1][n][ks], acc[m][2+n], 0, 0, 0);
        __builtin_amdgcn_s_setprio(0);
        __builtin_amdgcn_s_barrier();

        // ---- phase 2 (mh1, nh0): 8 ds_reads, stage A0(t+2) ----
        #pragma unroll
        for (int m = 0; m < 4; ++m)
            #pragma unroll
            for (int ks = 0; ks < 2; ++ks)
                a[m][ks] = rd(sA1, wr*64 + m*16 + lr, ks);
        if (t+2 < NTK) stage(A, aRow0, &sA[b][0][0], t+2);
        __builtin_amdgcn_s_barrier();
        asm volatile("s_waitcnt lgkmcnt(0)" ::: "memory");
        __builtin_amdgcn_sched_barrier(0);
        __builtin_amdgcn_s_setprio(1);
        #pragma unroll
        for (int m = 0; m < 4; ++m)
          #pragma unroll
          for (int n = 0; n < 2; ++n)
            #pragma unroll
            for (int ks = 0; ks < 2; ++ks)
                acc[4+m][n] = __builtin_amdgcn_mfma_f32_16x16x32_bf16(a[m][ks], bb[0][n][ks], acc[4+m][n], 0, 0, 0);
        __builtin_amdgcn_s_setprio(0);
        __builtin_amdgcn_s_barrier();

        // ---- phase 3 (mh1, nh1): 0 ds_reads, stage B0(t+2) ----
        if (t+2 < NTK) stage(B, bRow0, &sB[b][0][0], t+2);
        if (t == NTK-2) asm volatile("s_waitcnt vmcnt(4)" ::: "memory");
        else            asm volatile("s_waitcnt vmcnt(8)" ::: "memory");
        __builtin_amdgcn_s_barrier();
        __builtin_amdgcn_s_setprio(1);
        #pragma unroll
        for (int m = 0; m < 4; ++m)
          #pragma unroll
          for (int n = 0; n < 2; ++n)
            #pragma unroll
            for (int ks = 0; ks < 2; ++ks)
                acc[4+m][2+n] = __builtin_amdgcn_mfma_f32_16x16x32_bf16(a[m][ks], bb[1][n][ks], acc[4+m][2+n], 0, 0, 0);
        __builtin_amdgcn_s_setprio(0);
        __builtin_amdgcn_s_barrier();
    }

    // epilogue: C = acc + bias   (C/D map: col = lane&15, row = (lane>>4)*4 + r)
    #pragma unroll
    for (int nh = 0; nh < 2; ++nh)
      #pragma unroll
      for (int n = 0; n < 2; ++n) {
        const int col = bx*BN + nh*128 + wc*32 + n*16 + lr;
        const float bv = bias[col];
        #pragma unroll
        for (int mh = 0; mh < 2; ++mh)
          #pragma unroll
          for (int m = 0; m < 4; ++m) {
            const int grow = by*BM + mh*128 + wr*64 + m*16 + lsl*4;
            #pragma unroll
            for (int r = 0; r < 4; ++r)
                C[(size_t)(grow + r)*OUT_F + col] = acc[mh*4+m][nh*2+n][r] + bv;
          }
      }
}

// ---------------- fallback (ws too small): fused fp32, slow but correct -----
__global__ __launch_bounds__(256) void fallback_kernel(
    const float* __restrict__ x, const float* __restrict__ P,
    const float* __restrict__ R, const float* __restrict__ pb,
    const float* __restrict__ gmin, const float* __restrict__ scale,
    const float4* __restrict__ H, float* __restrict__ out)
{
    __shared__ float s_s[IN_F];
    __shared__ float s_x[IN_F];
    int row = blockIdx.x;
    const float* xr = x + (size_t)row*IN_F;
    for (int f = threadIdx.x; f < IN_F; f += 256) {
        float xi = xr[f];
        float xn = (xi - gmin[f]) * scale[f];
        xn = fminf(fmaxf(xn, 0.f), (float)(KNOTS-1));
        int idx = (int)xn;  idx = idx > (KNOTS-2) ? (KNOTS-2) : idx;
        float tt = xn - (float)idx;
        float4 h = H[(size_t)f*KNOTS + idx];
        float t2 = tt*tt, t3 = t2*tt;
        s_s[f] = (2.f*t3-3.f*t2+1.f)*h.x + (-2.f*t3+3.f*t2)*h.y
               + (t3-2.f*t2+tt)*h.z + (t3-t2)*h.w;
        s_x[f] = xi;
    }
    __syncthreads();
    for (int j = 0; j < 4; ++j) {
        int o = threadIdx.x + j*256;
        const float* Pr = P + (size_t)o*IN_F;
        const float* Rr = R + (size_t)o*IN_F;
        float acc = pb[o];
        for (int f = 0; f < IN_F; ++f)
            acc = fmaf(s_s[f], Pr[f], fmaf(s_x[f], Rr[f], acc));
        out[(size_t)row*OUT_F + o] = acc;
    }
}

extern "C" void kernel_launch(void* const* d_in, const int* in_sizes, int n_in,
                              void* d_out, int out_size, void* d_ws, size_t ws_size,
                              hipStream_t stream) {
    const float* x         = (const float*)d_in[0];
    const float* grid      = (const float*)d_in[1];
    const float* coeffs    = (const float*)d_in[2];
    const float* tangents  = (const float*)d_in[3];
    const float* knotalive = (const float*)d_in[4];
    const float* proj_w    = (const float*)d_in[5];
    const float* proj_b    = (const float*)d_in[6];
    const float* res_w     = (const float*)d_in[7];
    float* out = (float*)d_out;

    const size_t needB  = (size_t)OUT_F * GK * 2;                 // 4 MiB
    const size_t needA  = (size_t)M_ROWS * GK * 2;                // 64 MiB
    const size_t needT  = ((size_t)IN_F*2 + (size_t)IN_F*KNOTS*4) * 4;

    char* ws = (char*)d_ws;
    if (ws_size >= needB + needA + needT) {
        unsigned short* Bcat = (unsigned short*)ws;
        unsigned short* Abuf = (unsigned short*)(ws + needB);
        float*  gmin = (float*)(ws + needB + needA);
        float*  scl  = gmin + IN_F;
        float4* H    = (float4*)(scl + IN_F);

        prep_kernel<<<(IN_F+255)/256, 256, 0, stream>>>(grid, coeffs, tangents, knotalive,
                                                        gmin, scl, H);
        bcast_kernel<<<(OUT_F*GK/4)/256, 256, 0, stream>>>(proj_w, res_w, Bcat);
        spline_kernel<<<dim3(M_ROWS/SROWS, IN_F/256), 256, 0, stream>>>(x, gmin, scl, H, Abuf);
        gemm_kernel<<<(M_ROWS/BM)*(OUT_F/BN), 512, 0, stream>>>(Abuf, Bcat, proj_b, out);
    } else {
        float*  gmin = (float*)ws;
        float*  scl  = gmin + IN_F;
        float4* H    = (float4*)(scl + IN_F);
        prep_kernel<<<(IN_F+255)/256, 256, 0, stream>>>(grid, coeffs, tangents, knotalive,
                                                        gmin, scl, H);
        fallback_kernel<<<M_ROWS, 256, 0, stream>>>(x, proj_w, res_w, proj_b,
                                                    gmin, scl, H, out);
    }
}

// Round 6
// 107.009 us; speedup vs baseline: 1.4500x; 1.0045x over previous
//
#include <hip/hip_runtime.h>
#include <hip/hip_bf16.h>

// out = spline(x) @ proj_w^T + x @ res_w^T + proj_b
// A_bf16 = [spline(x) | x] : (16384, 2048),  Bcat_bf16 = [proj_w | res_w] : (1024, 2048)

#define IN_F   1024
#define OUT_F  1024
#define KNOTS  12
#define M_ROWS 16384
#define GK     2048

// ---- GEMM: 256x256 tile, BK=64, 8 waves, 4-phase/K-tile ----
#define BM   256
#define BN   256
#define BKT  64
#define NTK  (GK / BKT)     // 32 K-tiles

typedef __attribute__((ext_vector_type(8))) __bf16 bf16x8;
typedef __attribute__((ext_vector_type(4))) float  f32x4;

__device__ __forceinline__ unsigned short f2bf(float v) {
    unsigned int u = __float_as_uint(v);
    u = (u + 0x7fffu + ((u >> 16) & 1u)) >> 16;   // RNE
    return (unsigned short)u;
}

__device__ __forceinline__ void gload16(const void* g, void* l) {
    __builtin_amdgcn_global_load_lds(
        (const __attribute__((address_space(1))) void*)g,
        (__attribute__((address_space(3))) void*)l, 16, 0, 0);
}

// ---------------- prep: sort knots, fold sigmoid, build float4 Hermite table
__global__ __launch_bounds__(256) void prep_kernel(
    const float* __restrict__ grid, const float* __restrict__ coeffs,
    const float* __restrict__ tangents, const float* __restrict__ alive,
    float* __restrict__ gmin, float* __restrict__ scale, float4* __restrict__ H)
{
    int f = blockIdx.x * blockDim.x + threadIdx.x;
    if (f >= IN_F) return;
    float g[KNOTS], c[KNOTS], t[KNOTS], a[KNOTS];
    for (int i = 0; i < KNOTS; ++i) {
        g[i] = grid[f*KNOTS+i];  c[i] = coeffs[f*KNOTS+i];
        t[i] = tangents[f*KNOTS+i]; a[i] = alive[f*KNOTS+i];
    }
    for (int i = 1; i < KNOTS; ++i) {       // stable insertion sort on g
        float gk=g[i], ck=c[i], tk=t[i], ak=a[i];
        int j = i-1;
        while (j >= 0 && g[j] > gk) { g[j+1]=g[j]; c[j+1]=c[j]; t[j+1]=t[j]; a[j+1]=a[j]; --j; }
        g[j+1]=gk; c[j+1]=ck; t[j+1]=tk; a[j+1]=ak;
    }
    float mcl[KNOTS], mtl[KNOTS];
    for (int i = 0; i < KNOTS; ++i) {
        float s = 1.f / (1.f + expf(-a[i]));
        mcl[i] = c[i]*s;  mtl[i] = t[i]*s;
    }
    gmin[f] = g[0];
    float grange = fmaxf(g[KNOTS-1] - g[0], 1e-6f);
    scale[f] = (float)(KNOTS-1) / grange;
    for (int k = 0; k < KNOTS-1; ++k) {
        float dx = fmaxf(g[k+1]-g[k], 1e-6f);
        H[(size_t)f*KNOTS + k] = make_float4(mcl[k], mcl[k+1], mtl[k]*dx, mtl[k+1]*dx);
    }
    H[(size_t)f*KNOTS + KNOTS-1] = make_float4(0.f, 0.f, 0.f, 0.f);
}

// ---------------- spline + cast:  A = [spline(x) | x]  bf16 -----------------
#define SROWS 64
#define HPAD  13
__global__ __launch_bounds__(256) void spline_kernel(const float* __restrict__ x,
    const float* __restrict__ gmin, const float* __restrict__ scale,
    const float4* __restrict__ H, unsigned short* __restrict__ A)
{
    __shared__ float4 sH[256 * HPAD];     // 52 KiB
    __shared__ float  sGm[256], sSc[256];
    const int tid  = threadIdx.x;
    const int fblk = blockIdx.y * 256;
    #pragma unroll
    for (int k = 0; k < KNOTS; ++k) sH[tid*HPAD + k] = H[(size_t)(fblk+tid)*KNOTS + k];
    sGm[tid] = gmin[fblk+tid];
    sSc[tid] = scale[fblk+tid];
    __syncthreads();

    const int wave = tid >> 6, lane = tid & 63;
    const int f0 = lane * 4;
    const float4 gm4 = *reinterpret_cast<const float4*>(&sGm[f0]);
    const float4 sc4 = *reinterpret_cast<const float4*>(&sSc[f0]);
    const float gms[4] = {gm4.x, gm4.y, gm4.z, gm4.w};
    const float scs[4] = {sc4.x, sc4.y, sc4.z, sc4.w};
    const int r0 = blockIdx.x * SROWS;

    #pragma unroll 2
    for (int r = wave; r < SROWS; r += 4) {
        const int row = r0 + r;
        const float4 xv = *reinterpret_cast<const float4*>(x + (size_t)row*IN_F + fblk + f0);
        const float xs[4] = {xv.x, xv.y, xv.z, xv.w};
        ushort4 so, xo;
        unsigned short* sp = (unsigned short*)&so;
        unsigned short* xp = (unsigned short*)&xo;
        #pragma unroll
        for (int j = 0; j < 4; ++j) {
            const float xi = xs[j];
            float xn = (xi - gms[j]) * scs[j];
            xn = fminf(fmaxf(xn, 0.f), (float)(KNOTS-1));
            int idx = (int)xn;  idx = idx > (KNOTS-2) ? (KNOTS-2) : idx;
            const float tt = xn - (float)idx;
            const float4 h = sH[(f0+j)*HPAD + idx];
            const float t2 = tt*tt, t3 = t2*tt;
            const float h00 =  2.f*t3 - 3.f*t2 + 1.f;
            const float h01 = -2.f*t3 + 3.f*t2;
            const float h10 =  t3 - 2.f*t2 + tt;
            const float h11 =  t3 - t2;
            sp[j] = f2bf(h00*h.x + h01*h.y + h10*h.z + h11*h.w);
            xp[j] = f2bf(xi);
        }
        const size_t base = (size_t)row * GK + fblk + f0;
        *reinterpret_cast<ushort4*>(A + base)        = so;
        *reinterpret_cast<ushort4*>(A + base + IN_F) = xo;
    }
}

// ---------------- B cast: Bcat = [proj_w | res_w] bf16 ----------------------
__global__ __launch_bounds__(256) void bcast_kernel(
    const float* __restrict__ P, const float* __restrict__ R,
    unsigned short* __restrict__ Bc)
{
    int g = blockIdx.x*256 + threadIdx.x;
    int n  = g >> 9;
    int k4 = (g & 511) * 4;
    const float* src = (k4 < IN_F) ? (P + (size_t)n*IN_F + k4)
                                   : (R + (size_t)n*IN_F + (k4 - IN_F));
    float4 v = *reinterpret_cast<const float4*>(src);
    ushort4 o;
    o.x = f2bf(v.x); o.y = f2bf(v.y); o.z = f2bf(v.z); o.w = f2bf(v.w);
    *reinterpret_cast<ushort4*>(Bc + (size_t)n*GK + k4) = o;
}

// ---------------- GEMM: C = A @ Bcat^T + bias (4-phase, compiler-scheduled) -
// Phases = output quadrants (mh, nh). Wave-uniform LDS halves; restage >=2
// phases after last reader. Buffer protocol: counted vmcnt + barrier pairs.
// NOTE: no explicit lgkmcnt(0)/sched_barrier before MFMA — ds_reads are
// compiler loads, so hipcc emits fine-grained lgkmcnt(N) interleaved with
// the MFMA cluster (r109); forcing a full drain was the R5 stall.
__global__ __launch_bounds__(512, 2) void gemm_kernel(
    const unsigned short* __restrict__ A, const unsigned short* __restrict__ B,
    const float* __restrict__ bias, float* __restrict__ C)
{
    __shared__ unsigned short sA[2][2][128*64];   // [buf][half] 16KiB each
    __shared__ unsigned short sB[2][2][128*64];   // total 128 KiB

    const int tid  = threadIdx.x;
    const int wg   = blockIdx.x;                  // 256 wgs, %8==0 bijective
    const int swzb = (wg & 7) * 32 + (wg >> 3);
    const int by   = swzb >> 2;                   // 0..63
    const int bx   = swzb & 3;                    // 0..3

    const int lane = tid & 63;
    const int wave = tid >> 6;
    const int wr   = wave >> 2;      // 0..1
    const int wc   = wave & 3;       // 0..3
    const int lr   = lane & 15;
    const int lsl  = lane >> 4;      // 0..3

    const size_t aRow0 = (size_t)by * BM;
    const size_t bRow0 = (size_t)bx * BN;

    auto stage = [&](const unsigned short* __restrict__ G, size_t gRow0,
                     unsigned short* lds, int ts) {
        const int k0 = ts * BKT;
        #pragma unroll
        for (int i = 0; i < 2; ++i) {
            const int L16 = i*512 + tid;          // 16B units within half-tile
            const int lrow = L16 >> 3;            // 0..127
            const int ss = (L16 & 7) ^ (lrow & 7);  // pre-swizzled source slot
            gload16(G + (gRow0 + lrow)*GK + k0 + ss*8, lds + (size_t)L16*8);
        }
    };
    auto rd = [&](const unsigned short* s, int lrow, int ks) -> bf16x8 {
        const int sp = (ks*4 + lsl) ^ (lrow & 7);   // swizzled read slot
        return *reinterpret_cast<const bf16x8*>(s + lrow*64 + sp*8);
    };

    f32x4 acc[8][4] = {};
    bf16x8 a[4][2], bb[2][2][2];

    // prologue: A0(0) B0(0) A1(0) B1(0) A0(1) B0(1)  (12 gloads/wave)
    stage(A, aRow0,       &sA[0][0][0], 0);
    stage(B, bRow0,       &sB[0][0][0], 0);
    stage(A, aRow0 + 128, &sA[0][1][0], 0);
    stage(B, bRow0 + 128, &sB[0][1][0], 0);
    stage(A, aRow0,       &sA[1][0][0], 1);
    stage(B, bRow0,       &sB[1][0][0], 1);
    asm volatile("s_waitcnt vmcnt(8)" ::: "memory");   // A0(0),B0(0) landed
    __builtin_amdgcn_s_barrier();

    for (int t = 0; t < NTK; ++t) {
        const int b = t & 1;
        unsigned short* sA0 = &sA[b][0][0];
        unsigned short* sA1 = &sA[b][1][0];
        unsigned short* sB0 = &sB[b][0][0];
        unsigned short* sB1 = &sB[b][1][0];

        // ---- phase 0 (mh0, nh0): 12 ds_reads, stage A1(t+1) ----
        #pragma unroll
        for (int m = 0; m < 4; ++m)
            #pragma unroll
            for (int ks = 0; ks < 2; ++ks)
                a[m][ks] = rd(sA0, wr*64 + m*16 + lr, ks);
        #pragma unroll
        for (int n = 0; n < 2; ++n)
            #pragma unroll
            for (int ks = 0; ks < 2; ++ks)
                bb[0][n][ks] = rd(sB0, wc*32 + n*16 + lr, ks);
        if (t+1 < NTK) stage(A, aRow0 + 128, &sA[b^1][1][0], t+1);
        if (t == NTK-1) asm volatile("s_waitcnt vmcnt(0)" ::: "memory");
        else            asm volatile("s_waitcnt vmcnt(6)" ::: "memory");
        __builtin_amdgcn_s_barrier();
        __builtin_amdgcn_s_setprio(1);
        #pragma unroll
        for (int m = 0; m < 4; ++m)
          #pragma unroll
          for (int n = 0; n < 2; ++n)
            #pragma unroll
            for (int ks = 0; ks < 2; ++ks)
                acc[m][n] = __builtin_amdgcn_mfma_f32_16x16x32_bf16(a[m][ks], bb[0][n][ks], acc[m][n], 0, 0, 0);
        __builtin_amdgcn_s_setprio(0);
        __builtin_amdgcn_s_barrier();

        // ---- phase 1 (mh0, nh1): 4 ds_reads, stage B1(t+1) ----
        #pragma unroll
        for (int n = 0; n < 2; ++n)
            #pragma unroll
            for (int ks = 0; ks < 2; ++ks)
                bb[1][n][ks] = rd(sB1, wc*32 + n*16 + lr, ks);
        if (t+1 < NTK) stage(B, bRow0 + 128, &sB[b^1][1][0], t+1);
        asm volatile("s_waitcnt vmcnt(10)" ::: "memory");
        __builtin_amdgcn_s_barrier();
        __builtin_amdgcn_s_setprio(1);
        #pragma unroll
        for (int m = 0; m < 4; ++m)
          #pragma unroll
          for (int n = 0; n < 2; ++n)
            #pragma unroll
            for (int ks = 0; ks < 2; ++ks)
                acc[m][2+n] = __builtin_amdgcn_mfma_f32_16x16x32_bf16(a[m][ks], bb[1][n][ks], acc[m][2+n], 0, 0, 0);
        __builtin_amdgcn_s_setprio(0);
        __builtin_amdgcn_s_barrier();

        // ---- phase 2 (mh1, nh0): 8 ds_reads, stage A0(t+2) ----
        #pragma unroll
        for (int m = 0; m < 4; ++m)
            #pragma unroll
            for (int ks = 0; ks < 2; ++ks)
                a[m][ks] = rd(sA1, wr*64 + m*16 + lr, ks);
        if (t+2 < NTK) stage(A, aRow0, &sA[b][0][0], t+2);
        __builtin_amdgcn_s_barrier();
        __builtin_amdgcn_s_setprio(1);
        #pragma unroll
        for (int m = 0; m < 4; ++m)
          #pragma unroll
          for (int n = 0; n < 2; ++n)
            #pragma unroll
            for (int ks = 0; ks < 2; ++ks)
                acc[4+m][n] = __builtin_amdgcn_mfma_f32_16x16x32_bf16(a[m][ks], bb[0][n][ks], acc[4+m][n], 0, 0, 0);
        __builtin_amdgcn_s_setprio(0);
        __builtin_amdgcn_s_barrier();

        // ---- phase 3 (mh1, nh1): 0 ds_reads, stage B0(t+2) ----
        if (t+2 < NTK) stage(B, bRow0, &sB[b][0][0], t+2);
        if (t == NTK-2) asm volatile("s_waitcnt vmcnt(4)" ::: "memory");
        else            asm volatile("s_waitcnt vmcnt(8)" ::: "memory");
        __builtin_amdgcn_s_barrier();
        __builtin_amdgcn_s_setprio(1);
        #pragma unroll
        for (int m = 0; m < 4; ++m)
          #pragma unroll
          for (int n = 0; n < 2; ++n)
            #pragma unroll
            for (int ks = 0; ks < 2; ++ks)
                acc[4+m][2+n] = __builtin_amdgcn_mfma_f32_16x16x32_bf16(a[m][ks], bb[1][n][ks], acc[4+m][2+n], 0, 0, 0);
        __builtin_amdgcn_s_setprio(0);
        __builtin_amdgcn_s_barrier();
    }

    // epilogue: C = acc + bias   (C/D map: col = lane&15, row = (lane>>4)*4 + r)
    #pragma unroll
    for (int nh = 0; nh < 2; ++nh)
      #pragma unroll
      for (int n = 0; n < 2; ++n) {
        const int col = bx*BN + nh*128 + wc*32 + n*16 + lr;
        const float bv = bias[col];
        #pragma unroll
        for (int mh = 0; mh < 2; ++mh)
          #pragma unroll
          for (int m = 0; m < 4; ++m) {
            const int grow = by*BM + mh*128 + wr*64 + m*16 + lsl*4;
            #pragma unroll
            for (int r = 0; r < 4; ++r)
                C[(size_t)(grow + r)*OUT_F + col] = acc[mh*4+m][nh*2+n][r] + bv;
          }
      }
}

// ---------------- fallback (ws too small): fused fp32, slow but correct -----
__global__ __launch_bounds__(256) void fallback_kernel(
    const float* __restrict__ x, const float* __restrict__ P,
    const float* __restrict__ R, const float* __restrict__ pb,
    const float* __restrict__ gmin, const float* __restrict__ scale,
    const float4* __restrict__ H, float* __restrict__ out)
{
    __shared__ float s_s[IN_F];
    __shared__ float s_x[IN_F];
    int row = blockIdx.x;
    const float* xr = x + (size_t)row*IN_F;
    for (int f = threadIdx.x; f < IN_F; f += 256) {
        float xi = xr[f];
        float xn = (xi - gmin[f]) * scale[f];
        xn = fminf(fmaxf(xn, 0.f), (float)(KNOTS-1));
        int idx = (int)xn;  idx = idx > (KNOTS-2) ? (KNOTS-2) : idx;
        float tt = xn - (float)idx;
        float4 h = H[(size_t)f*KNOTS + idx];
        float t2 = tt*tt, t3 = t2*tt;
        s_s[f] = (2.f*t3-3.f*t2+1.f)*h.x + (-2.f*t3+3.f*t2)*h.y
               + (t3-2.f*t2+tt)*h.z + (t3-t2)*h.w;
        s_x[f] = xi;
    }
    __syncthreads();
    for (int j = 0; j < 4; ++j) {
        int o = threadIdx.x + j*256;
        const float* Pr = P + (size_t)o*IN_F;
        const float* Rr = R + (size_t)o*IN_F;
        float acc = pb[o];
        for (int f = 0; f < IN_F; ++f)
            acc = fmaf(s_s[f], Pr[f], fmaf(s_x[f], Rr[f], acc));
        out[(size_t)row*OUT_F + o] = acc;
    }
}

extern "C" void kernel_launch(void* const* d_in, const int* in_sizes, int n_in,
                              void* d_out, int out_size, void* d_ws, size_t ws_size,
                              hipStream_t stream) {
    const float* x         = (const float*)d_in[0];
    const float* grid      = (const float*)d_in[1];
    const float* coeffs    = (const float*)d_in[2];
    const float* tangents  = (const float*)d_in[3];
    const float* knotalive = (const float*)d_in[4];
    const float* proj_w    = (const float*)d_in[5];
    const float* proj_b    = (const float*)d_in[6];
    const float* res_w     = (const float*)d_in[7];
    float* out = (float*)d_out;

    const size_t needB  = (size_t)OUT_F * GK * 2;                 // 4 MiB
    const size_t needA  = (size_t)M_ROWS * GK * 2;                // 64 MiB
    const size_t needT  = ((size_t)IN_F*2 + (size_t)IN_F*KNOTS*4) * 4;

    char* ws = (char*)d_ws;
    if (ws_size >= needB + needA + needT) {
        unsigned short* Bcat = (unsigned short*)ws;
        unsigned short* Abuf = (unsigned short*)(ws + needB);
        float*  gmin = (float*)(ws + needB + needA);
        float*  scl  = gmin + IN_F;
        float4* H    = (float4*)(scl + IN_F);

        prep_kernel<<<(IN_F+255)/256, 256, 0, stream>>>(grid, coeffs, tangents, knotalive,
                                                        gmin, scl, H);
        bcast_kernel<<<(OUT_F*GK/4)/256, 256, 0, stream>>>(proj_w, res_w, Bcat);
        spline_kernel<<<dim3(M_ROWS/SROWS, IN_F/256), 256, 0, stream>>>(x, gmin, scl, H, Abuf);
        gemm_kernel<<<(M_ROWS/BM)*(OUT_F/BN), 512, 0, stream>>>(Abuf, Bcat, proj_b, out);
    } else {
        float*  gmin = (float*)ws;
        float*  scl  = gmin + IN_F;
        float4* H    = (float4*)(scl + IN_F);
        prep_kernel<<<(IN_F+255)/256, 256, 0, stream>>>(grid, coeffs, tangents, knotalive,
                                                        gmin, scl, H);
        fallback_kernel<<<M_ROWS, 256, 0, stream>>>(x, proj_w, res_w, proj_b,
                                                    gmin, scl, H, out);
    }
}